// Round 1
// baseline (164.057 us; speedup 1.0000x reference)
//
#include <hip/hip_runtime.h>

// Chamfer distance: x (32,2048,3) f32, y (32,2048,3) f32 -> scalar f32.
// out = mean_b[ mean_j min_i ||x[b,j]-y[b,i]||^2 + mean_i min_j ||.||^2 ]
//     = (sum of all 2*B*N per-point mins) / (B*N)   since N == M.

#define BATCH 32
#define NPTS 2048
#define TILE 256
#define TILES_PER_B (NPTS / TILE)            // 8
#define BLOCKS_PER_DIR (BATCH * TILES_PER_B) // 256

__global__ __launch_bounds__(256) void chamfer_min_kernel(
    const float* __restrict__ x, const float* __restrict__ y,
    float* __restrict__ partial)
{
    __shared__ float4 sref[NPTS];   // 32 KB, refs padded to float4
    __shared__ float  sred[4];

    const int bid   = blockIdx.x;
    const int dir   = bid >> 8;          // 0: queries=x refs=y, 1: swapped
    const int inner = bid & 255;
    const int b     = inner >> 3;
    const int tile  = inner & 7;
    const int tid   = threadIdx.x;

    const float* q = dir ? y : x;
    const float* r = dir ? x : y;
    const float* rb = r + (size_t)b * NPTS * 3;

    // Stage all refs of this batch into LDS, padded to float4.
    for (int p = tid; p < NPTS; p += 256) {
        const float a0 = rb[p * 3 + 0];
        const float a1 = rb[p * 3 + 1];
        const float a2 = rb[p * 3 + 2];
        sref[p] = make_float4(a0, a1, a2, 0.0f);
    }
    __syncthreads();

    // Each thread owns one query point.
    const int i = tile * TILE + tid;
    const float* qp = q + ((size_t)b * NPTS + i) * 3;
    const float qx = qp[0], qy = qp[1], qz = qp[2];

    float best = 3.4e38f;
    #pragma unroll 8
    for (int j = 0; j < NPTS; ++j) {
        const float4 rp = sref[j];      // broadcast ds_read_b128
        const float dx = qx - rp.x;
        const float dy = qy - rp.y;
        const float dz = qz - rp.z;
        const float d = dx * dx + dy * dy + dz * dz;
        best = fminf(best, d);
    }

    // Deterministic block sum of the 256 per-query mins.
    float s = best;
    #pragma unroll
    for (int off = 32; off > 0; off >>= 1) s += __shfl_down(s, off);
    if ((tid & 63) == 0) sred[tid >> 6] = s;
    __syncthreads();
    if (tid == 0) partial[bid] = sred[0] + sred[1] + sred[2] + sred[3];
}

__global__ __launch_bounds__(256) void chamfer_final_kernel(
    const float* __restrict__ partial, float* __restrict__ out)
{
    const int tid = threadIdx.x;
    float s = partial[tid] + partial[tid + 256];
    #pragma unroll
    for (int off = 32; off > 0; off >>= 1) s += __shfl_down(s, off);
    __shared__ float sred[4];
    if ((tid & 63) == 0) sred[tid >> 6] = s;
    __syncthreads();
    if (tid == 0)
        out[0] = (sred[0] + sred[1] + sred[2] + sred[3]) *
                 (1.0f / (float)(BATCH * NPTS));
}

extern "C" void kernel_launch(void* const* d_in, const int* in_sizes, int n_in,
                              void* d_out, int out_size, void* d_ws, size_t ws_size,
                              hipStream_t stream)
{
    const float* x = (const float*)d_in[0];
    const float* y = (const float*)d_in[1];
    float* partial = (float*)d_ws;            // 512 floats
    float* out     = (float*)d_out;

    chamfer_min_kernel<<<2 * BLOCKS_PER_DIR, 256, 0, stream>>>(x, y, partial);
    chamfer_final_kernel<<<1, 256, 0, stream>>>(partial, out);
}

// Round 2
// 69.468 us; speedup vs baseline: 2.3616x; 2.3616x over previous
//
#include <hip/hip_runtime.h>

// Chamfer distance: x (32,2048,3) f32, y (32,2048,3) f32 -> scalar f32.
// out = (sum over both directions of per-point nearest-neighbor sq-dists) / (B*N)
// since N == M == 2048.
//
// Layout: 1024 blocks x 64 threads (1 wave), Q=2 query points per thread.
//   block -> (dir, batch, tile of 128 queries); refs of the batch staged in
//   LDS as float4 (32 KB), broadcast-read per iteration.

#define BATCH 32
#define NPTS 2048
#define QPT 2                     // queries per thread
#define BLOCKT 64                 // threads per block (1 wave)
#define QPB (BLOCKT * QPT)        // 128 queries per block
#define TILES_PER_B (NPTS / QPB)  // 16
#define BLOCKS_TOTAL (2 * BATCH * TILES_PER_B) // 1024

__global__ __launch_bounds__(BLOCKT) void chamfer_min_kernel(
    const float* __restrict__ x, const float* __restrict__ y,
    float* __restrict__ partial)
{
    __shared__ float4 sref[NPTS];   // 32 KB

    const int bid   = blockIdx.x;
    const int dir   = bid >> 9;            // 512 blocks per direction
    const int inner = bid & 511;
    const int b     = inner >> 4;          // 16 tiles per batch
    const int tile  = inner & 15;
    const int tid   = threadIdx.x;

    const float* q  = dir ? y : x;
    const float* r  = dir ? x : y;
    const float* rb = r + (size_t)b * NPTS * 3;

    // Stage refs into LDS, padded to float4.
    for (int p = tid; p < NPTS; p += BLOCKT) {
        sref[p] = make_float4(rb[p * 3 + 0], rb[p * 3 + 1], rb[p * 3 + 2], 0.0f);
    }
    __syncthreads();

    // Two query points per thread.
    const int i0 = tile * QPB + tid;       // and i0 + 64
    const float* qp0 = q + ((size_t)b * NPTS + i0) * 3;
    const float* qp1 = qp0 + (size_t)BLOCKT * 3;
    const float q0x = qp0[0], q0y = qp0[1], q0z = qp0[2];
    const float q1x = qp1[0], q1y = qp1[1], q1z = qp1[2];

    float best0 = 3.4e38f, best1 = 3.4e38f;
    #pragma unroll 8
    for (int j = 0; j < NPTS; ++j) {
        const float4 rp = sref[j];          // broadcast ds_read_b128
        const float d0x = q0x - rp.x;
        const float d0y = q0y - rp.y;
        const float d0z = q0z - rp.z;
        const float d1x = q1x - rp.x;
        const float d1y = q1y - rp.y;
        const float d1z = q1z - rp.z;
        const float d0 = fmaf(d0x, d0x, fmaf(d0y, d0y, d0z * d0z));
        const float d1 = fmaf(d1x, d1x, fmaf(d1y, d1y, d1z * d1z));
        best0 = fminf(best0, d0);
        best1 = fminf(best1, d1);
    }

    // Single-wave deterministic sum of the 128 per-query mins.
    float s = best0 + best1;
    #pragma unroll
    for (int off = 32; off > 0; off >>= 1) s += __shfl_down(s, off);
    if (tid == 0) partial[bid] = s;
}

__global__ __launch_bounds__(256) void chamfer_final_kernel(
    const float* __restrict__ partial, float* __restrict__ out)
{
    const int tid = threadIdx.x;
    float s = partial[tid] + partial[tid + 256] +
              partial[tid + 512] + partial[tid + 768];
    #pragma unroll
    for (int off = 32; off > 0; off >>= 1) s += __shfl_down(s, off);
    __shared__ float sred[4];
    if ((tid & 63) == 0) sred[tid >> 6] = s;
    __syncthreads();
    if (tid == 0)
        out[0] = (sred[0] + sred[1] + sred[2] + sred[3]) *
                 (1.0f / (float)(BATCH * NPTS));
}

extern "C" void kernel_launch(void* const* d_in, const int* in_sizes, int n_in,
                              void* d_out, int out_size, void* d_ws, size_t ws_size,
                              hipStream_t stream)
{
    const float* x = (const float*)d_in[0];
    const float* y = (const float*)d_in[1];
    float* partial = (float*)d_ws;            // 1024 floats
    float* out     = (float*)d_out;

    chamfer_min_kernel<<<BLOCKS_TOTAL, BLOCKT, 0, stream>>>(x, y, partial);
    chamfer_final_kernel<<<1, 256, 0, stream>>>(partial, out);
}

// Round 3
// 40.214 us; speedup vs baseline: 4.0796x; 1.7275x over previous
//
#include <hip/hip_runtime.h>

// Chamfer distance: x (32,2048,3) f32, y (32,2048,3) f32 -> scalar f32.
// d(q,r) = |r|^2 - 2 q.r + |q|^2 ; |r|^2 staged in float4.w, |q|^2 added
// after the min (constant per query). Inner body: 3 FMA + 1 min per pair.
//
// Kernel1: 256 blocks x 256 threads. Block = (dir, batch, 512-query tile).
//   Each of the 4 waves scans a distinct 512-ref slice for the SAME 512
//   queries (8 per lane); per-wave mins combined via LDS, block-summed.
// Kernel2: sums the 256 block partials, scales by 1/(B*N).

#define BATCH 32
#define NPTS 2048

__global__ __launch_bounds__(256) void chamfer_min_kernel(
    const float* __restrict__ x, const float* __restrict__ y,
    float* __restrict__ partial)
{
    __shared__ float4 sref[NPTS];   // 32 KB, w = |r|^2
    __shared__ float4 pm[512];      // 8 KB: per-query mins, one lane per wave
    __shared__ float  sred[4];

    const int bid  = blockIdx.x;    // 256 blocks
    const int dir  = bid >> 7;
    const int b    = (bid >> 2) & 31;
    const int tile = bid & 3;       // which 512-query tile
    const int tid  = threadIdx.x;
    const int lane = tid & 63;
    const int wv   = tid >> 6;

    const float* q  = dir ? y : x;
    const float* r  = dir ? x : y;
    const float* rb = r + (size_t)b * NPTS * 3;

    // Stage refs, w = |r|^2.
    for (int p = tid; p < NPTS; p += 256) {
        const float rx = rb[3 * p + 0];
        const float ry = rb[3 * p + 1];
        const float rz = rb[3 * p + 2];
        sref[p] = make_float4(rx, ry, rz, fmaf(rx, rx, fmaf(ry, ry, rz * rz)));
    }
    __syncthreads();

    // 8 queries per lane (same set for all 4 waves).
    const float* qb = q + ((size_t)b * NPTS + tile * 512) * 3;
    float m2x[8], m2y[8], m2z[8], qn[8], best[8];
    #pragma unroll
    for (int k = 0; k < 8; ++k) {
        const float* qp = qb + (size_t)(lane + 64 * k) * 3;
        const float a = qp[0], c = qp[1], e = qp[2];
        m2x[k] = -2.0f * a;
        m2y[k] = -2.0f * c;
        m2z[k] = -2.0f * e;
        qn[k]  = fmaf(a, a, fmaf(c, c, e * e));
        best[k] = 3.4e38f;
    }

    // This wave's 512-ref slice.
    const int js = wv * 512;
    #pragma unroll 4
    for (int j = 0; j < 512; ++j) {
        const float4 rp = sref[js + j];
        #pragma unroll
        for (int k = 0; k < 8; ++k) {
            float t = fmaf(m2x[k], rp.x, rp.w);
            t = fmaf(m2y[k], rp.y, t);
            t = fmaf(m2z[k], rp.z, t);
            best[k] = fminf(best[k], t);
        }
    }

    // Per-wave slice mins -> LDS (component wv of pm[query]); +|q|^2 (same
    // constant added to every slice, so the cross-slice min is unaffected).
    #pragma unroll
    for (int k = 0; k < 8; ++k) {
        ((float*)&pm[lane + 64 * k])[wv] = best[k] + qn[k];
    }
    __syncthreads();

    // Combine across slices and block-sum (2 queries per thread).
    const float4 a0 = pm[tid];
    const float4 a1 = pm[tid + 256];
    float s = fminf(fminf(a0.x, a0.y), fminf(a0.z, a0.w)) +
              fminf(fminf(a1.x, a1.y), fminf(a1.z, a1.w));
    #pragma unroll
    for (int off = 32; off > 0; off >>= 1) s += __shfl_down(s, off);
    if (lane == 0) sred[wv] = s;
    __syncthreads();
    if (tid == 0) partial[bid] = sred[0] + sred[1] + sred[2] + sred[3];
}

__global__ __launch_bounds__(256) void chamfer_final_kernel(
    const float* __restrict__ partial, float* __restrict__ out)
{
    const int tid = threadIdx.x;
    float s = partial[tid];
    #pragma unroll
    for (int off = 32; off > 0; off >>= 1) s += __shfl_down(s, off);
    __shared__ float sred[4];
    if ((tid & 63) == 0) sred[tid >> 6] = s;
    __syncthreads();
    if (tid == 0)
        out[0] = (sred[0] + sred[1] + sred[2] + sred[3]) *
                 (1.0f / (float)(BATCH * NPTS));
}

extern "C" void kernel_launch(void* const* d_in, const int* in_sizes, int n_in,
                              void* d_out, int out_size, void* d_ws, size_t ws_size,
                              hipStream_t stream)
{
    const float* x = (const float*)d_in[0];
    const float* y = (const float*)d_in[1];
    float* partial = (float*)d_ws;            // 256 floats
    float* out     = (float*)d_out;

    chamfer_min_kernel<<<256, 256, 0, stream>>>(x, y, partial);
    chamfer_final_kernel<<<1, 256, 0, stream>>>(partial, out);
}

// Round 4
// 34.552 us; speedup vs baseline: 4.7481x; 1.1639x over previous
//
#include <hip/hip_runtime.h>

// Chamfer distance: x (32,2048,3) f32, y (32,2048,3) f32 -> scalar f32.
// d(q,r) = |r|^2 - 2 q.r + |q|^2. Refs are wave-uniform per iteration ->
// read via the SCALAR pipe (readfirstlane-forced uniform address => s_load),
// |r|^2 computed inline, per-query chains packed as float2 (v_pk_fma_f32).
//
// Kernel1: 512 blocks x 256 threads. Block = (dir, batch, 256-query tile).
//   Each of the 4 waves scans a distinct 512-ref slice (SGPR-resident refs)
//   for the SAME 256 queries (4/lane, as 2 float2 pairs); slice-mins
//   combined via a 4KB LDS buffer, then block-summed.
// Kernel2: sums the 512 block partials, scales by 1/(B*N).

#define BATCH 32
#define NPTS 2048

typedef float f32x2 __attribute__((ext_vector_type(2)));

__global__ __launch_bounds__(256) void chamfer_min_kernel(
    const float* __restrict__ x, const float* __restrict__ y,
    float* __restrict__ partial)
{
    __shared__ float4 pm[256];      // 4 KB: per-query slice mins (.x..w = wave)
    __shared__ float  sred[4];

    const int bid   = blockIdx.x;   // 512 blocks
    const int dir   = bid >> 8;
    const int b     = (bid >> 3) & 31;
    const int qtile = bid & 7;      // 8 tiles of 256 queries
    const int tid   = threadIdx.x;
    const int lane  = tid & 63;
    const int wv    = __builtin_amdgcn_readfirstlane(tid >> 6); // uniform!

    const float* q  = dir ? y : x;
    const float* r  = dir ? x : y;

    // This wave's 512-ref slice (uniform base -> scalar loads).
    const float* rs = r + ((size_t)b * NPTS + wv * 512) * 3;

    // 4 queries per lane, packed into 2 float2 chains.
    const float* qb = q + ((size_t)b * NPTS + qtile * 256) * 3;
    f32x2 m2x[2], m2y[2], m2z[2], qn2[2], best[2];
    #pragma unroll
    for (int p = 0; p < 2; ++p) {
        const float* qp0 = qb + (size_t)(lane + 64 * (2 * p + 0)) * 3;
        const float* qp1 = qb + (size_t)(lane + 64 * (2 * p + 1)) * 3;
        const float a0 = qp0[0], c0 = qp0[1], e0 = qp0[2];
        const float a1 = qp1[0], c1 = qp1[1], e1 = qp1[2];
        m2x[p] = (f32x2){-2.0f * a0, -2.0f * a1};
        m2y[p] = (f32x2){-2.0f * c0, -2.0f * c1};
        m2z[p] = (f32x2){-2.0f * e0, -2.0f * e1};
        qn2[p] = (f32x2){fmaf(a0, a0, fmaf(c0, c0, e0 * e0)),
                         fmaf(a1, a1, fmaf(c1, c1, e1 * e1))};
        best[p] = (f32x2){3.4e38f, 3.4e38f};
    }

    #pragma unroll 8
    for (int j = 0; j < 512; ++j) {
        const float rx = rs[3 * j + 0];     // wave-uniform -> s_load
        const float ry = rs[3 * j + 1];
        const float rz = rs[3 * j + 2];
        const float rn = fmaf(rx, rx, fmaf(ry, ry, rz * rz));
        const f32x2 rn2 = (f32x2){rn, rn};
        #pragma unroll
        for (int p = 0; p < 2; ++p) {
            f32x2 t = __builtin_elementwise_fma(m2x[p], (f32x2){rx, rx}, rn2);
            t = __builtin_elementwise_fma(m2y[p], (f32x2){ry, ry}, t);
            t = __builtin_elementwise_fma(m2z[p], (f32x2){rz, rz}, t);
            best[p] = __builtin_elementwise_min(best[p], t);
        }
    }

    // Per-wave slice mins (+|q|^2, constant across slices) -> LDS.
    #pragma unroll
    for (int p = 0; p < 2; ++p) {
        const f32x2 v = best[p] + qn2[p];
        ((float*)&pm[lane + 64 * (2 * p + 0)])[wv] = v.x;
        ((float*)&pm[lane + 64 * (2 * p + 1)])[wv] = v.y;
    }
    __syncthreads();

    // Combine across the 4 slices and block-sum (1 query per thread).
    const float4 a0 = pm[tid];
    float s = fminf(fminf(a0.x, a0.y), fminf(a0.z, a0.w));
    #pragma unroll
    for (int off = 32; off > 0; off >>= 1) s += __shfl_down(s, off);
    if (lane == 0) sred[tid >> 6] = s;
    __syncthreads();
    if (tid == 0) partial[bid] = sred[0] + sred[1] + sred[2] + sred[3];
}

__global__ __launch_bounds__(256) void chamfer_final_kernel(
    const float* __restrict__ partial, float* __restrict__ out)
{
    const int tid = threadIdx.x;
    float s = partial[tid] + partial[tid + 256];
    #pragma unroll
    for (int off = 32; off > 0; off >>= 1) s += __shfl_down(s, off);
    __shared__ float sred[4];
    if ((tid & 63) == 0) sred[tid >> 6] = s;
    __syncthreads();
    if (tid == 0)
        out[0] = (sred[0] + sred[1] + sred[2] + sred[3]) *
                 (1.0f / (float)(BATCH * NPTS));
}

extern "C" void kernel_launch(void* const* d_in, const int* in_sizes, int n_in,
                              void* d_out, int out_size, void* d_ws, size_t ws_size,
                              hipStream_t stream)
{
    const float* x = (const float*)d_in[0];
    const float* y = (const float*)d_in[1];
    float* partial = (float*)d_ws;            // 512 floats
    float* out     = (float*)d_out;

    chamfer_min_kernel<<<512, 256, 0, stream>>>(x, y, partial);
    chamfer_final_kernel<<<1, 256, 0, stream>>>(partial, out);
}